// Round 2
// baseline (314.352 us; speedup 1.0000x reference)
//
#include <hip/hip_runtime.h>
#include <hip/hip_bf16.h>

typedef __bf16 bf16x8 __attribute__((ext_vector_type(8)));
typedef float f32x4 __attribute__((ext_vector_type(4)));

#define MT 32   // tokens per block
#define CC 256

// swizzled LDS byte offset for element (r, c) of a [MT][256] bf16 tile:
// row stride 512B, XOR bits 4-6 with row&7 -> ds_read_b128 A-frags ~2-way (free)
__device__ __forceinline__ int swz(int r, int c) {
    return r * 512 + ((c * 2) ^ ((r & 7) << 4));
}

// Per-wave GEMM tile: A from swizzled LDS [MT][256] (k = 0..NKS*32), B from global
// transposed weights WT[col][wK] (k range b_k0 + 0..NKS*32), cols colbase..colbase+NREP*16.
template<int MREP, int NREP, int NKS>
__device__ __forceinline__ void mfma_tile(const __bf16* A_lds, const __bf16* __restrict__ WT,
                                          int wK, int colbase, int b_k0,
                                          f32x4 (&acc)[MREP][NREP], int r16, int q4)
{
#pragma unroll
    for (int ks = 0; ks < NKS; ++ks) {
        int ak = ks * 32 + q4 * 8;
        int bk = b_k0 + ks * 32 + q4 * 8;
        bf16x8 a[MREP], b[NREP];
#pragma unroll
        for (int mf = 0; mf < MREP; ++mf)
            a[mf] = *(const bf16x8*)((const char*)A_lds + swz(mf * 16 + r16, ak));
#pragma unroll
        for (int nf = 0; nf < NREP; ++nf)
            b[nf] = *(const bf16x8*)(WT + (size_t)(colbase + nf * 16 + r16) * wK + bk);
#pragma unroll
        for (int mf = 0; mf < MREP; ++mf)
#pragma unroll
            for (int nf = 0; nf < NREP; ++nf)
                acc[mf][nf] = __builtin_amdgcn_mfma_f32_16x16x32_bf16(a[mf], b[nf], acc[mf][nf], 0, 0, 0);
    }
}

__device__ __forceinline__ void zero4(f32x4 (&acc)[2][4]) {
#pragma unroll
    for (int i = 0; i < 2; ++i)
#pragma unroll
        for (int j = 0; j < 4; ++j)
            acc[i][j] = (f32x4){0.f, 0.f, 0.f, 0.f};
}

// staging: load 32x256 fp32 tile (8 float4/thread), convert bf16, swizzled LDS write
__device__ __forceinline__ void stage_load(const float* __restrict__ src, int row0, int tid,
                                           float4 (&v)[8]) {
#pragma unroll
    for (int i = 0; i < 8; ++i) {
        int f = i * 256 + tid;
        int r = f >> 6;
        int c = (f & 63) * 4;
        v[i] = *(const float4*)(src + (size_t)(row0 + r) * CC + c);
    }
}
__device__ __forceinline__ void stage_write(__bf16* dst, int tid, const float4 (&v)[8]) {
#pragma unroll
    for (int i = 0; i < 8; ++i) {
        int f = i * 256 + tid;
        int r = f >> 6;
        int c = (f & 63) * 4;
        union { __bf16 h[4]; unsigned long long u; } uu;
        uu.h[0] = (__bf16)v[i].x; uu.h[1] = (__bf16)v[i].y;
        uu.h[2] = (__bf16)v[i].z; uu.h[3] = (__bf16)v[i].w;
        *(unsigned long long*)((char*)dst + swz(r, c)) = uu.u;
    }
}

// single fused weight-prep: transpose + bf16-convert all weights into d_ws.
// layout (bf16 elem offsets):
//   WTqp   @ 0       [256][512]  (k<256: Wq,  k>=256: Wpos)
//   WTkp   @ 131072  [256][512]  (k<256: Wk,  k>=256: Wpos)
//   WTo1   @ 262144  [512][256]
//   WTo2   @ 393216  [64][512]
//   WTv    @ 425984  [256][256]
//   WTout  @ 491520  [256][256]
__global__ void prep_all(const float* __restrict__ Wq, const float* __restrict__ Wk,
                         const float* __restrict__ Wpos, const float* __restrict__ Wo1,
                         const float* __restrict__ Wo2, const float* __restrict__ Wv,
                         const float* __restrict__ Wout, __bf16* __restrict__ ws)
{
    int i = blockIdx.x * 256 + threadIdx.x;
    if (i >= 557056) return;
    float v;
    if (i < 131072) {
        int n = i >> 9, k = i & 511;
        v = (k < 256) ? Wq[k * 256 + n] : Wpos[(k - 256) * 256 + n];
    } else if (i < 262144) {
        int j = i - 131072, n = j >> 9, k = j & 511;
        v = (k < 256) ? Wk[k * 256 + n] : Wpos[(k - 256) * 256 + n];
    } else if (i < 393216) {
        int j = i - 262144, n = j >> 8, k = j & 255;
        v = Wo1[k * 512 + n];
    } else if (i < 425984) {
        int j = i - 393216, n = j >> 9, k = j & 511;
        v = Wo2[k * 64 + n];
    } else if (i < 491520) {
        int j = i - 425984, n = j >> 8, k = j & 255;
        v = Wv[k * 256 + n];
    } else {
        int j = i - 491520, n = j >> 8, k = j & 255;
        v = Wout[k * 256 + n];
    }
    ws[i] = (__bf16)v;
}

extern "C" __global__ void __launch_bounds__(256, 2)
fused_ext_attn(const float* __restrict__ query, const float* __restrict__ key,
               const float* __restrict__ value, const float* __restrict__ refp,
               const float* __restrict__ pose,
               const __bf16* __restrict__ ws,
               const float* __restrict__ bq, const float* __restrict__ bk,
               const float* __restrict__ bv, const float* __restrict__ bpos,
               const float* __restrict__ bo1, const float* __restrict__ bo2,
               const float* __restrict__ bout,
               float* __restrict__ out)
{
    const __bf16* WTqp  = ws;
    const __bf16* WTkp  = ws + 131072;
    const __bf16* WTo1  = ws + 262144;
    const __bf16* WTo2  = ws + 393216;
    const __bf16* WTv   = ws + 425984;
    const __bf16* WTout = ws + 491520;

    __shared__ __attribute__((aligned(16))) __bf16 SA[MT * CC];  // query -> k
    __shared__ __attribute__((aligned(16))) __bf16 SB[MT * CC];  // pose -> (free)
    __shared__ __attribute__((aligned(16))) __bf16 SC[MT * CC];  // key -> value
    __shared__ __attribute__((aligned(16))) __bf16 SD[MT * CC];  // h1 -> q -> o
    __shared__ float off_s[MT * 64];                             // [t][h*8+k*2+xy]
    __shared__ float wv_s[MT * 8];                               // [t][h]

    const int tid = threadIdx.x;
    const int lane = tid & 63;
    const int wid = tid >> 6;
    const int r16 = lane & 15;
    const int q4 = lane >> 4;
    const int row0 = blockIdx.x * MT;
    const int cb = wid * 64;

    f32x4 acc[2][4];
    f32x4 accO[2];   // offset-GEMM accumulator (NREP=1), persists across both passes

    // ---- step 1: stage query -> SA, pose -> SB ----
    {
        float4 vq[8], vp[8];
        stage_load(query, row0, tid, vq);
        stage_load(pose, row0, tid, vp);
        stage_write(SA, tid, vq);
        stage_write(SB, tid, vp);
    }
    __syncthreads();

    // ---- step 2: h1 pass0 = relu(query@Wo1[:, 0:256]) -> SD ; issue key loads early ----
    float4 vkey[8];
    stage_load(key, row0, tid, vkey);
    zero4(acc);
    mfma_tile<2, 4, 8>(SA, WTo1, 256, cb, 0, acc, r16, q4);
#pragma unroll
    for (int mf = 0; mf < 2; ++mf)
#pragma unroll
        for (int nf = 0; nf < 4; ++nf) {
            int col = cb + nf * 16 + r16;
            float bias = bo1[col];
#pragma unroll
            for (int r = 0; r < 4; ++r) {
                int row = mf * 16 + q4 * 4 + r;
                *(__bf16*)((char*)SD + swz(row, col)) = (__bf16)fmaxf(acc[mf][nf][r] + bias, 0.f);
            }
        }
    __syncthreads();

    // ---- step 3: off partial, k-slice 0:256; wave owns cols wid*16..+15, full K ----
    accO[0] = (f32x4){0.f, 0.f, 0.f, 0.f};
    accO[1] = (f32x4){0.f, 0.f, 0.f, 0.f};
    {
        f32x4 (&aO)[2][1] = *(f32x4(*)[2][1])&accO;
        mfma_tile<2, 1, 8>(SD, WTo2, 512, wid * 16, 0, aO, r16, q4);
    }
    __syncthreads();   // SD reads done before pass-1 overwrite

    // ---- step 4: h1 pass1 -> SD ; retire key staging into SC ----
    stage_write(SC, tid, vkey);
    zero4(acc);
    mfma_tile<2, 4, 8>(SA, WTo1, 256, 256 + cb, 0, acc, r16, q4);
#pragma unroll
    for (int mf = 0; mf < 2; ++mf)
#pragma unroll
        for (int nf = 0; nf < 4; ++nf) {
            int gcol = 256 + cb + nf * 16 + r16;
            int col = cb + nf * 16 + r16;
            float bias = bo1[gcol];
#pragma unroll
            for (int r = 0; r < 4; ++r) {
                int row = mf * 16 + q4 * 4 + r;
                *(__bf16*)((char*)SD + swz(row, col)) = (__bf16)fmaxf(acc[mf][nf][r] + bias, 0.f);
            }
        }
    __syncthreads();

    // ---- step 5: off partial, k-slice 256:512 ; write off_s = accO + bo2 ----
    {
        f32x4 (&aO)[2][1] = *(f32x4(*)[2][1])&accO;
        mfma_tile<2, 1, 8>(SD, WTo2, 512, wid * 16, 256, aO, r16, q4);
    }
    {
        int col = wid * 16 + r16;
        float b2 = bo2[col];
#pragma unroll
        for (int mf = 0; mf < 2; ++mf)
#pragma unroll
            for (int r = 0; r < 4; ++r)
                off_s[(mf * 16 + q4 * 4 + r) * 64 + col] = accO[mf][r] + b2;
    }
    __syncthreads();   // off_s visible; SD free

    // ---- step 6: q = [query|pose] @ WTqp + bq + bpos -> SD ----
    zero4(acc);
    mfma_tile<2, 4, 8>(SA, WTqp, 512, cb, 0, acc, r16, q4);
    mfma_tile<2, 4, 8>(SB, WTqp, 512, cb, 256, acc, r16, q4);
#pragma unroll
    for (int mf = 0; mf < 2; ++mf)
#pragma unroll
        for (int nf = 0; nf < 4; ++nf) {
            int col = cb + nf * 16 + r16;
            float bias = bq[col] + bpos[col];
#pragma unroll
            for (int r = 0; r < 4; ++r) {
                int row = mf * 16 + q4 * 4 + r;
                *(__bf16*)((char*)SD + swz(row, col)) = (__bf16)(acc[mf][nf][r] + bias);
            }
        }
    __syncthreads();   // SA free after this point

    // ---- step 7: k = [key|pose] @ WTkp + bk + bpos -> SA ; issue value loads early ----
    float4 vval[8];
    stage_load(value, row0, tid, vval);
    zero4(acc);
    mfma_tile<2, 4, 8>(SC, WTkp, 512, cb, 0, acc, r16, q4);
    mfma_tile<2, 4, 8>(SB, WTkp, 512, cb, 256, acc, r16, q4);
#pragma unroll
    for (int mf = 0; mf < 2; ++mf)
#pragma unroll
        for (int nf = 0; nf < 4; ++nf) {
            int col = cb + nf * 16 + r16;
            float bias = bk[col] + bpos[col];
#pragma unroll
            for (int r = 0; r < 4; ++r) {
                int row = mf * 16 + q4 * 4 + r;
                *(__bf16*)((char*)SA + swz(row, col)) = (__bf16)(acc[mf][nf][r] + bias);
            }
        }
    __syncthreads();   // SC free after this point

    // ---- step 8: scalar attention phase (1 (t,h) pair per thread) ; stage value -> SC ----
    stage_write(SC, tid, vval);
    {
        int t = tid >> 3, h = tid & 7;
        float qk = 0.f;
#pragma unroll
        for (int j = 0; j < 4; ++j) {
            int c = h * 32 + j * 8;
            bf16x8 qv = *(const bf16x8*)((const char*)SD + swz(t, c));
            bf16x8 kv = *(const bf16x8*)((const char*)SA + swz(t, c));
#pragma unroll
            for (int e = 0; e < 8; ++e) qk += (float)qv[e] * (float)kv[e];
        }
        float2 rp = *(const float2*)(refp + (size_t)(row0 + t) * 2);
        float wgt[4], lg[4];
        float m = -1e30f;
#pragma unroll
        for (int kk = 0; kk < 4; ++kk) {
            float2 o = *(const float2*)&off_s[t * 64 + (h * 4 + kk) * 2];
            float cx = rp.x + o.x - 0.5f, cy = rp.y + o.y - 0.5f;
            float wx = fmaxf(0.f, 1.f - fabsf(cx));
            float wy = fmaxf(0.f, 1.f - fabsf(cy));
            wgt[kk] = wx * wy;
            lg[kk] = qk * wgt[kk] * 0.17677669529663687f;  // 1/sqrt(32)
            m = fmaxf(m, lg[kk]);
        }
        float s = 0.f, sw = 0.f;
#pragma unroll
        for (int kk = 0; kk < 4; ++kk) {
            float e = __expf(lg[kk] - m);
            s += e;
            sw += e * wgt[kk];
        }
        wv_s[t * 8 + h] = sw / s;
    }
    __syncthreads();   // wv_s + SC(value) visible; SD free

    // ---- step 9: o = (value @ WTv + bv) * wv -> SD ----
    zero4(acc);
    mfma_tile<2, 4, 8>(SC, WTv, 256, cb, 0, acc, r16, q4);
#pragma unroll
    for (int mf = 0; mf < 2; ++mf)
#pragma unroll
        for (int nf = 0; nf < 4; ++nf) {
            int col = cb + nf * 16 + r16;
            float bias = bv[col];
#pragma unroll
            for (int r = 0; r < 4; ++r) {
                int row = mf * 16 + q4 * 4 + r;
                float wvv = wv_s[row * 8 + (col >> 5)];
                *(__bf16*)((char*)SD + swz(row, col)) = (__bf16)((acc[mf][nf][r] + bias) * wvv);
            }
        }
    __syncthreads();

    // ---- step 10: out = o @ WTout + bout ----
    zero4(acc);
    mfma_tile<2, 4, 8>(SD, WTout, 256, cb, 0, acc, r16, q4);
#pragma unroll
    for (int mf = 0; mf < 2; ++mf)
#pragma unroll
        for (int nf = 0; nf < 4; ++nf) {
            int col = cb + nf * 16 + r16;
            float bias = bout[col];
#pragma unroll
            for (int r = 0; r < 4; ++r) {
                int row = mf * 16 + q4 * 4 + r;
                out[(size_t)(row0 + row) * CC + col] = acc[mf][nf][r] + bias;
            }
        }
}

extern "C" void kernel_launch(void* const* d_in, const int* in_sizes, int n_in,
                              void* d_out, int out_size, void* d_ws, size_t ws_size,
                              hipStream_t stream)
{
    const float* query = (const float*)d_in[0];
    const float* key   = (const float*)d_in[1];
    const float* value = (const float*)d_in[2];
    const float* refp  = (const float*)d_in[3];
    const float* pose  = (const float*)d_in[4];
    const float* Wq  = (const float*)d_in[5];  const float* bq   = (const float*)d_in[6];
    const float* Wk  = (const float*)d_in[7];  const float* bk   = (const float*)d_in[8];
    const float* Wv  = (const float*)d_in[9];  const float* bv   = (const float*)d_in[10];
    const float* Wo1 = (const float*)d_in[11]; const float* bo1  = (const float*)d_in[12];
    const float* Wo2 = (const float*)d_in[13]; const float* bo2  = (const float*)d_in[14];
    const float* Wpos= (const float*)d_in[15]; const float* bpos = (const float*)d_in[16];
    const float* Wout= (const float*)d_in[17]; const float* bout = (const float*)d_in[18];

    __bf16* ws = (__bf16*)d_ws;

    prep_all<<<2176, 256, 0, stream>>>(Wq, Wk, Wpos, Wo1, Wo2, Wv, Wout, ws);

    fused_ext_attn<<<65536 / MT, 256, 0, stream>>>(
        query, key, value, refp, pose, ws,
        bq, bk, bv, bpos, bo1, bo2, bout,
        (float*)d_out);
}

// Round 3
// 311.009 us; speedup vs baseline: 1.0108x; 1.0108x over previous
//
#include <hip/hip_runtime.h>
#include <hip/hip_bf16.h>

typedef __bf16 bf16x8 __attribute__((ext_vector_type(8)));
typedef float f32x4 __attribute__((ext_vector_type(4)));

#define MT 32   // tokens per tile
#define CC 256

// swizzled LDS byte offset for element (r, c) of a [MT][256] bf16 tile
__device__ __forceinline__ int swz(int r, int c) {
    return r * 512 + ((c * 2) ^ ((r & 7) << 4));
}

template<int MREP, int NREP, int NKS>
__device__ __forceinline__ void mfma_tile(const __bf16* A_lds, const __bf16* __restrict__ WT,
                                          int wK, int colbase, int b_k0,
                                          f32x4 (&acc)[MREP][NREP], int r16, int q4)
{
#pragma unroll
    for (int ks = 0; ks < NKS; ++ks) {
        int ak = ks * 32 + q4 * 8;
        int bk = b_k0 + ks * 32 + q4 * 8;
        bf16x8 a[MREP], b[NREP];
#pragma unroll
        for (int mf = 0; mf < MREP; ++mf)
            a[mf] = *(const bf16x8*)((const char*)A_lds + swz(mf * 16 + r16, ak));
#pragma unroll
        for (int nf = 0; nf < NREP; ++nf)
            b[nf] = *(const bf16x8*)(WT + (size_t)(colbase + nf * 16 + r16) * wK + bk);
#pragma unroll
        for (int mf = 0; mf < MREP; ++mf)
#pragma unroll
            for (int nf = 0; nf < NREP; ++nf)
                acc[mf][nf] = __builtin_amdgcn_mfma_f32_16x16x32_bf16(a[mf], b[nf], acc[mf][nf], 0, 0, 0);
    }
}

__device__ __forceinline__ void zero4(f32x4 (&acc)[2][4]) {
#pragma unroll
    for (int i = 0; i < 2; ++i)
#pragma unroll
        for (int j = 0; j < 4; ++j)
            acc[i][j] = (f32x4){0.f, 0.f, 0.f, 0.f};
}

__device__ __forceinline__ void stage_load(const float* __restrict__ src, int row0, int tid,
                                           float4 (&v)[8]) {
#pragma unroll
    for (int i = 0; i < 8; ++i) {
        int f = i * 256 + tid;
        int r = f >> 6;
        int c = (f & 63) * 4;
        v[i] = *(const float4*)(src + (size_t)(row0 + r) * CC + c);
    }
}
__device__ __forceinline__ void stage_write(__bf16* dst, int tid, const float4 (&v)[8]) {
#pragma unroll
    for (int i = 0; i < 8; ++i) {
        int f = i * 256 + tid;
        int r = f >> 6;
        int c = (f & 63) * 4;
        union { __bf16 h[4]; unsigned long long u; } uu;
        uu.h[0] = (__bf16)v[i].x; uu.h[1] = (__bf16)v[i].y;
        uu.h[2] = (__bf16)v[i].z; uu.h[3] = (__bf16)v[i].w;
        *(unsigned long long*)((char*)dst + swz(r, c)) = uu.u;
    }
}

// weight prep: transpose + bf16 convert. layout (bf16 elem offsets):
//   WTqp @0 [256][512] (k<256: Wq, k>=256: Wpos) | WTkp @131072 [256][512]
//   WTo1 @262144 [512][256] | WTo2 @393216 [64][512] | WTv @425984 [256][256]
//   WTout @491520 [256][256]   (total 557056 bf16 = 1114112 B)
__global__ void prep_all(const float* __restrict__ Wq, const float* __restrict__ Wk,
                         const float* __restrict__ Wpos, const float* __restrict__ Wo1,
                         const float* __restrict__ Wo2, const float* __restrict__ Wv,
                         const float* __restrict__ Wout, __bf16* __restrict__ ws)
{
    int i = blockIdx.x * 256 + threadIdx.x;
    if (i >= 557056) return;
    float v;
    if (i < 131072) {
        int n = i >> 9, k = i & 511;
        v = (k < 256) ? Wq[k * 256 + n] : Wpos[(k - 256) * 256 + n];
    } else if (i < 262144) {
        int j = i - 131072, n = j >> 9, k = j & 511;
        v = (k < 256) ? Wk[k * 256 + n] : Wpos[(k - 256) * 256 + n];
    } else if (i < 393216) {
        int j = i - 262144, n = j >> 8, k = j & 255;
        v = Wo1[k * 512 + n];
    } else if (i < 425984) {
        int j = i - 393216, n = j >> 9, k = j & 511;
        v = Wo2[k * 64 + n];
    } else if (i < 491520) {
        int j = i - 425984, n = j >> 8, k = j & 255;
        v = Wv[k * 256 + n];
    } else {
        int j = i - 491520, n = j >> 8, k = j & 255;
        v = Wout[k * 256 + n];
    }
    ws[i] = (__bf16)v;
}

// ============ K1: query/key/pose -> wv [L*8 floats] ============
extern "C" __global__ void __launch_bounds__(256, 2)
k1_attn_weights(const float* __restrict__ query, const float* __restrict__ key,
                const float* __restrict__ pose, const float* __restrict__ refp,
                const __bf16* __restrict__ ws,
                const float* __restrict__ bq, const float* __restrict__ bk,
                const float* __restrict__ bpos, const float* __restrict__ bo1,
                const float* __restrict__ bo2,
                float* __restrict__ wv_g)
{
    const __bf16* WTqp = ws;
    const __bf16* WTkp = ws + 131072;
    const __bf16* WTo1 = ws + 262144;
    const __bf16* WTo2 = ws + 393216;

    __shared__ __attribute__((aligned(16))) __bf16 SA[MT * CC];  // query -> k
    __shared__ __attribute__((aligned(16))) __bf16 SB[MT * CC];  // pose
    __shared__ __attribute__((aligned(16))) __bf16 SC[MT * CC];  // key
    __shared__ __attribute__((aligned(16))) __bf16 SD[MT * CC];  // h1 -> q
    __shared__ float off_s[MT * 64];

    const int tid = threadIdx.x;
    const int lane = tid & 63;
    const int wid = tid >> 6;
    const int r16 = lane & 15;
    const int q4 = lane >> 4;
    const int row0 = blockIdx.x * MT;
    const int cb = wid * 64;

    f32x4 acc[2][4];
    f32x4 accO[2];

    // P1: stage query, pose
    {
        float4 vq[8], vp[8];
        stage_load(query, row0, tid, vq);
        stage_load(pose, row0, tid, vp);
        stage_write(SA, tid, vq);
        stage_write(SB, tid, vp);
    }
    __syncthreads();                                   // B1

    // P2: h1 pass0 -> SD ; issue key loads (retire in P4)
    float4 vkey[8];
    stage_load(key, row0, tid, vkey);
    zero4(acc);
    mfma_tile<2, 4, 8>(SA, WTo1, 256, cb, 0, acc, r16, q4);
#pragma unroll
    for (int mf = 0; mf < 2; ++mf)
#pragma unroll
        for (int nf = 0; nf < 4; ++nf) {
            int col = cb + nf * 16 + r16;
            float bias = bo1[col];
#pragma unroll
            for (int r = 0; r < 4; ++r)
                *(__bf16*)((char*)SD + swz(mf * 16 + q4 * 4 + r, col)) =
                    (__bf16)fmaxf(acc[mf][nf][r] + bias, 0.f);
        }
    __syncthreads();                                   // B2

    // P3: off partial (k 0:256), wave owns cols wid*16..+15
    accO[0] = (f32x4){0.f, 0.f, 0.f, 0.f};
    accO[1] = (f32x4){0.f, 0.f, 0.f, 0.f};
    {
        f32x4 (&aO)[2][1] = *(f32x4(*)[2][1])&accO;
        mfma_tile<2, 1, 8>(SD, WTo2, 512, wid * 16, 0, aO, r16, q4);
    }
    __syncthreads();                                   // B3 (SD reads done)

    // P4: h1 pass1 -> SD ; retire key into SC
    stage_write(SC, tid, vkey);
    zero4(acc);
    mfma_tile<2, 4, 8>(SA, WTo1, 256, 256 + cb, 0, acc, r16, q4);
#pragma unroll
    for (int mf = 0; mf < 2; ++mf)
#pragma unroll
        for (int nf = 0; nf < 4; ++nf) {
            int col = cb + nf * 16 + r16;
            float bias = bo1[256 + col];
#pragma unroll
            for (int r = 0; r < 4; ++r)
                *(__bf16*)((char*)SD + swz(mf * 16 + q4 * 4 + r, col)) =
                    (__bf16)fmaxf(acc[mf][nf][r] + bias, 0.f);
        }
    __syncthreads();                                   // B4

    // P5: off partial (k 256:512); write off_s
    {
        f32x4 (&aO)[2][1] = *(f32x4(*)[2][1])&accO;
        mfma_tile<2, 1, 8>(SD, WTo2, 512, wid * 16, 256, aO, r16, q4);
    }
    {
        int col = wid * 16 + r16;
        float b2 = bo2[col];
#pragma unroll
        for (int mf = 0; mf < 2; ++mf)
#pragma unroll
            for (int r = 0; r < 4; ++r)
                off_s[(mf * 16 + q4 * 4 + r) * 64 + col] = accO[mf][r] + b2;
    }
    __syncthreads();                                   // B5 (off_s ready; SD free)

    // P6: q = [query|pose] @ WTqp -> SD
    zero4(acc);
    mfma_tile<2, 4, 8>(SA, WTqp, 512, cb, 0, acc, r16, q4);
    mfma_tile<2, 4, 8>(SB, WTqp, 512, cb, 256, acc, r16, q4);
#pragma unroll
    for (int mf = 0; mf < 2; ++mf)
#pragma unroll
        for (int nf = 0; nf < 4; ++nf) {
            int col = cb + nf * 16 + r16;
            float bias = bq[col] + bpos[col];
#pragma unroll
            for (int r = 0; r < 4; ++r)
                *(__bf16*)((char*)SD + swz(mf * 16 + q4 * 4 + r, col)) =
                    (__bf16)(acc[mf][nf][r] + bias);
        }
    __syncthreads();                                   // B6 (SA free)

    // P7: k = [key|pose] @ WTkp -> SA
    zero4(acc);
    mfma_tile<2, 4, 8>(SC, WTkp, 512, cb, 0, acc, r16, q4);
    mfma_tile<2, 4, 8>(SB, WTkp, 512, cb, 256, acc, r16, q4);
#pragma unroll
    for (int mf = 0; mf < 2; ++mf)
#pragma unroll
        for (int nf = 0; nf < 4; ++nf) {
            int col = cb + nf * 16 + r16;
            float bias = bk[col] + bpos[col];
#pragma unroll
            for (int r = 0; r < 4; ++r)
                *(__bf16*)((char*)SA + swz(mf * 16 + q4 * 4 + r, col)) =
                    (__bf16)(acc[mf][nf][r] + bias);
        }
    __syncthreads();                                   // B7

    // P8: scalar attention -> wv_g (global, fp32)
    {
        int t = tid >> 3, h = tid & 7;
        float qk = 0.f;
#pragma unroll
        for (int j = 0; j < 4; ++j) {
            int c = h * 32 + j * 8;
            bf16x8 qv = *(const bf16x8*)((const char*)SD + swz(t, c));
            bf16x8 kv = *(const bf16x8*)((const char*)SA + swz(t, c));
#pragma unroll
            for (int e = 0; e < 8; ++e) qk += (float)qv[e] * (float)kv[e];
        }
        float2 rp = *(const float2*)(refp + (size_t)(row0 + t) * 2);
        float wgt[4], lg[4];
        float m = -1e30f;
#pragma unroll
        for (int kk = 0; kk < 4; ++kk) {
            float2 o = *(const float2*)&off_s[t * 64 + (h * 4 + kk) * 2];
            float cx = rp.x + o.x - 0.5f, cy = rp.y + o.y - 0.5f;
            float wx = fmaxf(0.f, 1.f - fabsf(cx));
            float wy = fmaxf(0.f, 1.f - fabsf(cy));
            wgt[kk] = wx * wy;
            lg[kk] = qk * wgt[kk] * 0.17677669529663687f;  // 1/sqrt(32)
            m = fmaxf(m, lg[kk]);
        }
        float s = 0.f, sw = 0.f;
#pragma unroll
        for (int kk = 0; kk < 4; ++kk) {
            float e = __expf(lg[kk] - m);
            s += e;
            sw += e * wgt[kk];
        }
        wv_g[(size_t)(row0 + t) * 8 + h] = sw / s;
    }
}

// ============ K2: value + wv -> out ============
extern "C" __global__ void __launch_bounds__(256, 4)
k2_output(const float* __restrict__ value, const float* __restrict__ wv_g,
          const __bf16* __restrict__ ws,
          const float* __restrict__ bv, const float* __restrict__ bout,
          float* __restrict__ out)
{
    const __bf16* WTv   = ws + 425984;
    const __bf16* WTout = ws + 491520;

    __shared__ __attribute__((aligned(16))) __bf16 SC[MT * CC];  // value
    __shared__ __attribute__((aligned(16))) __bf16 SD[MT * CC];  // o = v*wv
    __shared__ float wv_s[MT * 8];

    const int tid = threadIdx.x;
    const int lane = tid & 63;
    const int wid = tid >> 6;
    const int r16 = lane & 15;
    const int q4 = lane >> 4;
    const int row0 = blockIdx.x * MT;
    const int cb = wid * 64;

    f32x4 acc[2][4];

    // P1: stage value -> SC, wv tile -> wv_s
    {
        float4 vv[8];
        stage_load(value, row0, tid, vv);
        wv_s[tid] = wv_g[(size_t)row0 * 8 + tid];
        stage_write(SC, tid, vv);
    }
    __syncthreads();

    // P2: o = (value @ WTv + bv) * wv -> SD
    zero4(acc);
    mfma_tile<2, 4, 8>(SC, WTv, 256, cb, 0, acc, r16, q4);
#pragma unroll
    for (int mf = 0; mf < 2; ++mf)
#pragma unroll
        for (int nf = 0; nf < 4; ++nf) {
            int col = cb + nf * 16 + r16;
            float bias = bv[col];
#pragma unroll
            for (int r = 0; r < 4; ++r) {
                int row = mf * 16 + q4 * 4 + r;
                float wvv = wv_s[row * 8 + (col >> 5)];
                *(__bf16*)((char*)SD + swz(row, col)) = (__bf16)((acc[mf][nf][r] + bias) * wvv);
            }
        }
    __syncthreads();

    // P3: out = o @ WTout + bout
    zero4(acc);
    mfma_tile<2, 4, 8>(SD, WTout, 256, cb, 0, acc, r16, q4);
#pragma unroll
    for (int mf = 0; mf < 2; ++mf)
#pragma unroll
        for (int nf = 0; nf < 4; ++nf) {
            int col = cb + nf * 16 + r16;
            float bias = bout[col];
#pragma unroll
            for (int r = 0; r < 4; ++r) {
                int row = mf * 16 + q4 * 4 + r;
                out[(size_t)(row0 + row) * CC + col] = acc[mf][nf][r] + bias;
            }
        }
}

extern "C" void kernel_launch(void* const* d_in, const int* in_sizes, int n_in,
                              void* d_out, int out_size, void* d_ws, size_t ws_size,
                              hipStream_t stream)
{
    const float* query = (const float*)d_in[0];
    const float* key   = (const float*)d_in[1];
    const float* value = (const float*)d_in[2];
    const float* refp  = (const float*)d_in[3];
    const float* pose  = (const float*)d_in[4];
    const float* Wq  = (const float*)d_in[5];  const float* bq   = (const float*)d_in[6];
    const float* Wk  = (const float*)d_in[7];  const float* bk   = (const float*)d_in[8];
    const float* Wv  = (const float*)d_in[9];  const float* bv   = (const float*)d_in[10];
    const float* Wo1 = (const float*)d_in[11]; const float* bo1  = (const float*)d_in[12];
    const float* Wo2 = (const float*)d_in[13]; const float* bo2  = (const float*)d_in[14];
    const float* Wpos= (const float*)d_in[15]; const float* bpos = (const float*)d_in[16];
    const float* Wout= (const float*)d_in[17]; const float* bout = (const float*)d_in[18];

    __bf16* ws = (__bf16*)d_ws;
    float* wv_g = (float*)((char*)d_ws + 1114112);   // 2 MB after weights

    prep_all<<<2176, 256, 0, stream>>>(Wq, Wk, Wpos, Wo1, Wo2, Wv, Wout, ws);

    k1_attn_weights<<<65536 / MT, 256, 0, stream>>>(
        query, key, pose, refp, ws, bq, bk, bpos, bo1, bo2, wv_g);

    k2_output<<<65536 / MT, 256, 0, stream>>>(
        value, wv_g, ws, bv, bout, (float*)d_out);
}

// Round 5
// 303.723 us; speedup vs baseline: 1.0350x; 1.0240x over previous
//
#include <hip/hip_runtime.h>
#include <hip/hip_bf16.h>

typedef __bf16 bf16x8 __attribute__((ext_vector_type(8)));
typedef float f32x4 __attribute__((ext_vector_type(4)));
typedef float f32x2 __attribute__((ext_vector_type(2)));

#define MT 32   // tokens per tile
#define CC 256

// swizzled LDS byte offset for element (r, c) of a [MT][256] bf16 tile
__device__ __forceinline__ int swz(int r, int c) {
    return r * 512 + ((c * 2) ^ ((r & 7) << 4));
}

template<int MREP, int NREP, int NKS>
__device__ __forceinline__ void mfma_tile(const __bf16* A_lds, const __bf16* __restrict__ WT,
                                          int wK, int colbase, int b_k0,
                                          f32x4 (&acc)[MREP][NREP], int r16, int q4)
{
#pragma unroll
    for (int ks = 0; ks < NKS; ++ks) {
        int ak = ks * 32 + q4 * 8;
        int bk = b_k0 + ks * 32 + q4 * 8;
        bf16x8 a[MREP], b[NREP];
#pragma unroll
        for (int mf = 0; mf < MREP; ++mf)
            a[mf] = *(const bf16x8*)((const char*)A_lds + swz(mf * 16 + r16, ak));
#pragma unroll
        for (int nf = 0; nf < NREP; ++nf)
            b[nf] = *(const bf16x8*)(WT + (size_t)(colbase + nf * 16 + r16) * wK + bk);
#pragma unroll
        for (int mf = 0; mf < MREP; ++mf)
#pragma unroll
            for (int nf = 0; nf < NREP; ++nf)
                acc[mf][nf] = __builtin_amdgcn_mfma_f32_16x16x32_bf16(a[mf], b[nf], acc[mf][nf], 0, 0, 0);
    }
}

__device__ __forceinline__ void zero4(f32x4 (&acc)[2][4]) {
#pragma unroll
    for (int i = 0; i < 2; ++i)
#pragma unroll
        for (int j = 0; j < 4; ++j)
            acc[i][j] = (f32x4){0.f, 0.f, 0.f, 0.f};
}

// non-temporal staging: activations are single-use streams — keep them out of L2
// so the (heavily reused) weight matrices stay resident.
__device__ __forceinline__ void stage_load(const float* __restrict__ src, int row0, int tid,
                                           f32x4 (&v)[8]) {
#pragma unroll
    for (int i = 0; i < 8; ++i) {
        int f = i * 256 + tid;
        int r = f >> 6;
        int c = (f & 63) * 4;
        v[i] = __builtin_nontemporal_load((const f32x4*)(src + (size_t)(row0 + r) * CC + c));
    }
}
__device__ __forceinline__ void stage_write(__bf16* dst, int tid, const f32x4 (&v)[8]) {
#pragma unroll
    for (int i = 0; i < 8; ++i) {
        int f = i * 256 + tid;
        int r = f >> 6;
        int c = (f & 63) * 4;
        union { __bf16 h[4]; unsigned long long u; } uu;
        uu.h[0] = (__bf16)v[i][0]; uu.h[1] = (__bf16)v[i][1];
        uu.h[2] = (__bf16)v[i][2]; uu.h[3] = (__bf16)v[i][3];
        *(unsigned long long*)((char*)dst + swz(r, c)) = uu.u;
    }
}

// weight prep: transpose + bf16 convert. layout (bf16 elem offsets):
//   WTqp @0 [256][512] (k<256: Wq, k>=256: Wpos) | WTkp @131072 [256][512]
//   WTo1 @262144 [512][256] | WTo2 @393216 [64][512] | WTv @425984 [256][256]
//   WTout @491520 [256][256]   (total 557056 bf16 = 1114112 B)
__global__ void prep_all(const float* __restrict__ Wq, const float* __restrict__ Wk,
                         const float* __restrict__ Wpos, const float* __restrict__ Wo1,
                         const float* __restrict__ Wo2, const float* __restrict__ Wv,
                         const float* __restrict__ Wout, __bf16* __restrict__ ws)
{
    int i = blockIdx.x * 256 + threadIdx.x;
    if (i >= 557056) return;
    float v;
    if (i < 131072) {
        int n = i >> 9, k = i & 511;
        v = (k < 256) ? Wq[k * 256 + n] : Wpos[(k - 256) * 256 + n];
    } else if (i < 262144) {
        int j = i - 131072, n = j >> 9, k = j & 511;
        v = (k < 256) ? Wk[k * 256 + n] : Wpos[(k - 256) * 256 + n];
    } else if (i < 393216) {
        int j = i - 262144, n = j >> 8, k = j & 255;
        v = Wo1[k * 512 + n];
    } else if (i < 425984) {
        int j = i - 393216, n = j >> 9, k = j & 511;
        v = Wo2[k * 64 + n];
    } else if (i < 491520) {
        int j = i - 425984, n = j >> 8, k = j & 255;
        v = Wv[k * 256 + n];
    } else {
        int j = i - 491520, n = j >> 8, k = j & 255;
        v = Wout[k * 256 + n];
    }
    ws[i] = (__bf16)v;
}

// ============ K1: query/key/pose -> wv [L*8 floats] ============
extern "C" __global__ void __launch_bounds__(256, 2)
k1_attn_weights(const float* __restrict__ query, const float* __restrict__ key,
                const float* __restrict__ pose, const float* __restrict__ refp,
                const __bf16* __restrict__ ws,
                const float* __restrict__ bq, const float* __restrict__ bk,
                const float* __restrict__ bpos, const float* __restrict__ bo1,
                const float* __restrict__ bo2,
                float* __restrict__ wv_g)
{
    const __bf16* WTqp = ws;
    const __bf16* WTkp = ws + 131072;
    const __bf16* WTo1 = ws + 262144;
    const __bf16* WTo2 = ws + 393216;

    __shared__ __attribute__((aligned(16))) __bf16 SA[MT * CC];  // query -> k
    __shared__ __attribute__((aligned(16))) __bf16 SB[MT * CC];  // pose
    __shared__ __attribute__((aligned(16))) __bf16 SC[MT * CC];  // key
    __shared__ __attribute__((aligned(16))) __bf16 SD[MT * CC];  // h1 -> q
    __shared__ float off_s[MT * 64];

    const int tid = threadIdx.x;
    const int lane = tid & 63;
    const int wid = tid >> 6;
    const int r16 = lane & 15;
    const int q4 = lane >> 4;
    const int row0 = blockIdx.x * MT;
    const int cb = wid * 64;

    f32x4 acc[2][4];
    f32x4 accO[2];

    // P1: stage query, pose
    {
        f32x4 vq[8], vp[8];
        stage_load(query, row0, tid, vq);
        stage_load(pose, row0, tid, vp);
        stage_write(SA, tid, vq);
        stage_write(SB, tid, vp);
    }
    __syncthreads();                                   // B1

    // P2: h1 pass0 -> SD ; issue key loads (retire in P4)
    f32x4 vkey[8];
    stage_load(key, row0, tid, vkey);
    zero4(acc);
    mfma_tile<2, 4, 8>(SA, WTo1, 256, cb, 0, acc, r16, q4);
#pragma unroll
    for (int mf = 0; mf < 2; ++mf)
#pragma unroll
        for (int nf = 0; nf < 4; ++nf) {
            int col = cb + nf * 16 + r16;
            float bias = bo1[col];
#pragma unroll
            for (int r = 0; r < 4; ++r)
                *(__bf16*)((char*)SD + swz(mf * 16 + q4 * 4 + r, col)) =
                    (__bf16)fmaxf(acc[mf][nf][r] + bias, 0.f);
        }
    __syncthreads();                                   // B2

    // P3: off partial (k 0:256), wave owns cols wid*16..+15
    accO[0] = (f32x4){0.f, 0.f, 0.f, 0.f};
    accO[1] = (f32x4){0.f, 0.f, 0.f, 0.f};
    {
        f32x4 (&aO)[2][1] = *(f32x4(*)[2][1])&accO;
        mfma_tile<2, 1, 8>(SD, WTo2, 512, wid * 16, 0, aO, r16, q4);
    }
    __syncthreads();                                   // B3 (SD reads done)

    // P4: h1 pass1 -> SD ; retire key into SC
    stage_write(SC, tid, vkey);
    zero4(acc);
    mfma_tile<2, 4, 8>(SA, WTo1, 256, 256 + cb, 0, acc, r16, q4);
#pragma unroll
    for (int mf = 0; mf < 2; ++mf)
#pragma unroll
        for (int nf = 0; nf < 4; ++nf) {
            int col = cb + nf * 16 + r16;
            float bias = bo1[256 + col];
#pragma unroll
            for (int r = 0; r < 4; ++r)
                *(__bf16*)((char*)SD + swz(mf * 16 + q4 * 4 + r, col)) =
                    (__bf16)fmaxf(acc[mf][nf][r] + bias, 0.f);
        }
    __syncthreads();                                   // B4

    // P5: off partial (k 256:512); write off_s
    {
        f32x4 (&aO)[2][1] = *(f32x4(*)[2][1])&accO;
        mfma_tile<2, 1, 8>(SD, WTo2, 512, wid * 16, 256, aO, r16, q4);
    }
    {
        int col = wid * 16 + r16;
        float b2 = bo2[col];
#pragma unroll
        for (int mf = 0; mf < 2; ++mf)
#pragma unroll
            for (int r = 0; r < 4; ++r)
                off_s[(mf * 16 + q4 * 4 + r) * 64 + col] = accO[mf][r] + b2;
    }
    __syncthreads();                                   // B5 (off_s ready; SD free)

    // P6: q = [query|pose] @ WTqp -> SD
    zero4(acc);
    mfma_tile<2, 4, 8>(SA, WTqp, 512, cb, 0, acc, r16, q4);
    mfma_tile<2, 4, 8>(SB, WTqp, 512, cb, 256, acc, r16, q4);
#pragma unroll
    for (int mf = 0; mf < 2; ++mf)
#pragma unroll
        for (int nf = 0; nf < 4; ++nf) {
            int col = cb + nf * 16 + r16;
            float bias = bq[col] + bpos[col];
#pragma unroll
            for (int r = 0; r < 4; ++r)
                *(__bf16*)((char*)SD + swz(mf * 16 + q4 * 4 + r, col)) =
                    (__bf16)(acc[mf][nf][r] + bias);
        }
    __syncthreads();                                   // B6 (SA free)

    // P7: k = [key|pose] @ WTkp -> SA
    zero4(acc);
    mfma_tile<2, 4, 8>(SC, WTkp, 512, cb, 0, acc, r16, q4);
    mfma_tile<2, 4, 8>(SB, WTkp, 512, cb, 256, acc, r16, q4);
#pragma unroll
    for (int mf = 0; mf < 2; ++mf)
#pragma unroll
        for (int nf = 0; nf < 4; ++nf) {
            int col = cb + nf * 16 + r16;
            float bias = bk[col] + bpos[col];
#pragma unroll
            for (int r = 0; r < 4; ++r)
                *(__bf16*)((char*)SA + swz(mf * 16 + q4 * 4 + r, col)) =
                    (__bf16)(acc[mf][nf][r] + bias);
        }
    __syncthreads();                                   // B7

    // P8: scalar attention -> wv_g (global, fp32, streaming)
    {
        int t = tid >> 3, h = tid & 7;
        float qk = 0.f;
#pragma unroll
        for (int j = 0; j < 4; ++j) {
            int c = h * 32 + j * 8;
            bf16x8 qv = *(const bf16x8*)((const char*)SD + swz(t, c));
            bf16x8 kv = *(const bf16x8*)((const char*)SA + swz(t, c));
#pragma unroll
            for (int e = 0; e < 8; ++e) qk += (float)qv[e] * (float)kv[e];
        }
        f32x2 rp = __builtin_nontemporal_load((const f32x2*)(refp + (size_t)(row0 + t) * 2));
        float wgt[4], lg[4];
        float m = -1e30f;
#pragma unroll
        for (int kk = 0; kk < 4; ++kk) {
            float2 o = *(const float2*)&off_s[t * 64 + (h * 4 + kk) * 2];
            float cx = rp[0] + o.x - 0.5f, cy = rp[1] + o.y - 0.5f;
            float wx = fmaxf(0.f, 1.f - fabsf(cx));
            float wy = fmaxf(0.f, 1.f - fabsf(cy));
            wgt[kk] = wx * wy;
            lg[kk] = qk * wgt[kk] * 0.17677669529663687f;  // 1/sqrt(32)
            m = fmaxf(m, lg[kk]);
        }
        float s = 0.f, sw = 0.f;
#pragma unroll
        for (int kk = 0; kk < 4; ++kk) {
            float e = __expf(lg[kk] - m);
            s += e;
            sw += e * wgt[kk];
        }
        __builtin_nontemporal_store(sw / s, wv_g + (size_t)(row0 + t) * 8 + h);
    }
}

// ============ K2: value + wv -> out ============
extern "C" __global__ void __launch_bounds__(256, 4)
k2_output(const float* __restrict__ value, const float* __restrict__ wv_g,
          const __bf16* __restrict__ ws,
          const float* __restrict__ bv, const float* __restrict__ bout,
          float* __restrict__ out)
{
    const __bf16* WTv   = ws + 425984;
    const __bf16* WTout = ws + 491520;

    __shared__ __attribute__((aligned(16))) __bf16 SC[MT * CC];  // value
    __shared__ __attribute__((aligned(16))) __bf16 SD[MT * CC];  // o = v*wv
    __shared__ float wv_s[MT * 8];

    const int tid = threadIdx.x;
    const int lane = tid & 63;
    const int wid = tid >> 6;
    const int r16 = lane & 15;
    const int q4 = lane >> 4;
    const int row0 = blockIdx.x * MT;
    const int cb = wid * 64;

    f32x4 acc[2][4];

    // P1: stage value -> SC, wv tile -> wv_s
    {
        f32x4 vv[8];
        stage_load(value, row0, tid, vv);
        wv_s[tid] = wv_g[(size_t)row0 * 8 + tid];
        stage_write(SC, tid, vv);
    }
    __syncthreads();

    // P2: o = (value @ WTv + bv) * wv -> SD
    zero4(acc);
    mfma_tile<2, 4, 8>(SC, WTv, 256, cb, 0, acc, r16, q4);
#pragma unroll
    for (int mf = 0; mf < 2; ++mf)
#pragma unroll
        for (int nf = 0; nf < 4; ++nf) {
            int col = cb + nf * 16 + r16;
            float bias = bv[col];
#pragma unroll
            for (int r = 0; r < 4; ++r) {
                int row = mf * 16 + q4 * 4 + r;
                float wvv = wv_s[row * 8 + (col >> 5)];
                *(__bf16*)((char*)SD + swz(row, col)) = (__bf16)((acc[mf][nf][r] + bias) * wvv);
            }
        }
    __syncthreads();

    // P3: out = o @ WTout + bout (streaming store)
    zero4(acc);
    mfma_tile<2, 4, 8>(SD, WTout, 256, cb, 0, acc, r16, q4);
#pragma unroll
    for (int mf = 0; mf < 2; ++mf)
#pragma unroll
        for (int nf = 0; nf < 4; ++nf) {
            int col = cb + nf * 16 + r16;
            float bias = bout[col];
#pragma unroll
            for (int r = 0; r < 4; ++r) {
                int row = mf * 16 + q4 * 4 + r;
                __builtin_nontemporal_store(acc[mf][nf][r] + bias,
                                            out + (size_t)(row0 + row) * CC + col);
            }
        }
}

extern "C" void kernel_launch(void* const* d_in, const int* in_sizes, int n_in,
                              void* d_out, int out_size, void* d_ws, size_t ws_size,
                              hipStream_t stream)
{
    const float* query = (const float*)d_in[0];
    const float* key   = (const float*)d_in[1];
    const float* value = (const float*)d_in[2];
    const float* refp  = (const float*)d_in[3];
    const float* pose  = (const float*)d_in[4];
    const float* Wq  = (const float*)d_in[5];  const float* bq   = (const float*)d_in[6];
    const float* Wk  = (const float*)d_in[7];  const float* bk   = (const float*)d_in[8];
    const float* Wv  = (const float*)d_in[9];  const float* bv   = (const float*)d_in[10];
    const float* Wo1 = (const float*)d_in[11]; const float* bo1  = (const float*)d_in[12];
    const float* Wo2 = (const float*)d_in[13]; const float* bo2  = (const float*)d_in[14];
    const float* Wpos= (const float*)d_in[15]; const float* bpos = (const float*)d_in[16];
    const float* Wout= (const float*)d_in[17]; const float* bout = (const float*)d_in[18];

    __bf16* ws = (__bf16*)d_ws;
    float* wv_g = (float*)((char*)d_ws + 1114112);   // 2 MB after weights

    prep_all<<<2176, 256, 0, stream>>>(Wq, Wk, Wpos, Wo1, Wo2, Wv, Wout, ws);

    k1_attn_weights<<<65536 / MT, 256, 0, stream>>>(
        query, key, pose, refp, ws, bq, bk, bpos, bo1, bo2, wv_g);

    k2_output<<<65536 / MT, 256, 0, stream>>>(
        value, wv_g, ws, bv, bout, (float*)d_out);
}